// Round 30
// baseline (308.806 us; speedup 1.0000x reference)
//
#include <hip/hip_runtime.h>

#define NN 50000
#define EE 800000
#define RR 16
#define BBASES 8
#define SLOPE 0.01f
#define BCAP 16          // total per-(dst,rel) capacity (2 dense + 14 overflow)
#define OVF (BCAP - 2)
#define SLICE 16384      // 128*128 elems per W slice
#define NS 9             // GEMM K-slices: 8 basis-combos (xs) + 1 self (from Ain)
#define XS_S 8           // xs slices per node
#define LSTRIDE (NS * SLICE)
#define MROWS 50048      // NN padded (multiple of 64)
#define CCAP 25088       // chunk cap: xs chunk = 51.3 MB -> L3-resident w/ feature table
#define D1B 256          // k_dense1 blocks
#define NPART 6250       // NN / 8 (dst partition width)

typedef __attribute__((ext_vector_type(8))) short short8;
typedef __attribute__((ext_vector_type(4))) float f32x4;

static __device__ __forceinline__ ushort f2b(float f) {
    unsigned u = __float_as_uint(f);
    unsigned r = (u + 0x7FFF + ((u >> 16) & 1)) >> 16;
    return (ushort)r;
}
static __device__ __forceinline__ float b2f(ushort h) {
    return __uint_as_float(((unsigned)h) << 16);
}

// ---- prep: Bt both layers (8 transposed basis slices + wloop^T) + x->bf16 + zero curNR ----
__global__ __launch_bounds__(256) void k_prep(
    const float* __restrict__ basis1, const float* __restrict__ basis2,
    const float* __restrict__ wloop1, const float* __restrict__ wloop2,
    const float* __restrict__ x, ushort* __restrict__ xb,
    ushort* __restrict__ Wt, int* __restrict__ curNR)
{
    const long WTN = 2 * BBASES * SLICE;           // 262144 (basis transpose)
    const long WLN = 2 * SLICE;                    // 32768  (wloop transpose)
    const long CVT = (long)NN * 128 / 4;           // 1.6M (4 elems each)
    const long total = WTN + WLN + CVT + (long)NN * RR;
    for (long t = (long)blockIdx.x * blockDim.x + threadIdx.x; t < total;
         t += (long)gridDim.x * blockDim.x) {
        if (t < WTN) {
            int l = (int)(t >> 17);
            int rem = (int)(t & 131071);
            int b = rem >> 14;
            int kn = rem & 16383;
            int k = kn >> 7, n = kn & 127;
            const float* bs = l ? basis2 : basis1;
            Wt[(long)l * LSTRIDE + (long)b * SLICE + n * 128 + k] =
                f2b(bs[(long)b * SLICE + kn]);
        } else if (t < WTN + WLN) {
            int j = (int)(t - WTN);
            int l = j >> 14;
            int kn = j & 16383;
            int k = kn >> 7, n = kn & 127;
            const float* wl = l ? wloop2 : wloop1;
            Wt[(long)l * LSTRIDE + (NS - 1) * SLICE + n * 128 + k] = f2b(wl[kn]);
        } else if (t < WTN + WLN + CVT) {
            long i = t - WTN - WLN;
            float4 v = reinterpret_cast<const float4*>(x)[i];
            ushort4 o;
            o.x = f2b(v.x); o.y = f2b(v.y); o.z = f2b(v.z); o.w = f2b(v.w);
            reinterpret_cast<ushort4*>(xb)[i] = o;
        } else {
            curNR[(long)(t - WTN - WLN - CVT)] = 0;
        }
    }
}

// ---- bucket edges by (dst, rel), dst-partitioned by blockIdx&7 (XCD heuristic) ----
__global__ __launch_bounds__(256) void k_bucket(
    const int* __restrict__ src, const int* __restrict__ dst,
    const int* __restrict__ etype, int* __restrict__ curNR,
    uint* __restrict__ bslot01, ushort* __restrict__ bovf)
{
    int part = blockIdx.x & 7;
    int bg = blockIdx.x >> 3;               // 0..255 block-groups per partition
    int dlo = part * NPART, dhi = dlo + NPART;
    for (long t = (long)bg * blockDim.x + threadIdx.x; t < EE;
         t += 256L * blockDim.x) {
        int d = __builtin_nontemporal_load(dst + t);
        if (d < dlo || d >= dhi) continue;
        int e = __builtin_nontemporal_load(etype + t);
        int s = __builtin_nontemporal_load(src + t);
        int idx = d * RR + e;
        int pos = atomicAdd(curNR + idx, 1);
        if (pos < 2)
            reinterpret_cast<ushort*>(bslot01)[idx * 2 + pos] = (ushort)s;
        else if (pos < BCAP)
            bovf[(size_t)idx * OVF + (pos - 2)] = (ushort)s;
    }
}

// ---- gather+combine: one wave per node. Per relation r compute edge-sum (f32),
//      accumulate into 8 basis-combo accumulators via coeff[r][b] (uniform scalars). ----
__global__ __launch_bounds__(256) void k_gather(
    const ushort* __restrict__ Ain,    // [NN][128] bf16
    const int* __restrict__ cnt,       // [NN*16]
    const uint* __restrict__ bslot01,  // [NN*16] slot0|slot1 packed
    const ushort* __restrict__ bovf,   // [NN*16][OVF]
    const float* __restrict__ coeff,   // [RR][BBASES] (layer-specific)
    ushort* __restrict__ xs,           // [C][XS_S][128] bf16 (chunk-local)
    int n0, int ncnt)
{
    int idx = (int)(((long)blockIdx.x * blockDim.x + threadIdx.x) >> 6);
    int lane = threadIdx.x & 63;
    if (idx >= ncnt) return;
    int node = __builtin_amdgcn_readfirstlane(n0 + idx);
    if (node >= NN) return;
    int lo = lane * 2;

    ushort* orow = xs + (size_t)idx * (XS_S * 128) + lo;

    float sx[BBASES], sy[BBASES];
#pragma unroll
    for (int b = 0; b < BBASES; ++b) { sx[b] = 0.f; sy[b] = 0.f; }

#pragma unroll 4
    for (int r = 0; r < RR; ++r) {
        int c = cnt[node * RR + r];                          // wave-uniform -> scalar load
        c = min(c, BCAP);
        if (c == 0) continue;
        unsigned ss = bslot01[node * RR + r];                 // slot0|slot1, scalar load
        unsigned u0 = *reinterpret_cast<const unsigned*>(
            Ain + (size_t)(ss & 0xFFFFu) * 128 + lo);
        float ax = b2f((ushort)(u0 & 0xFFFF));
        float ay = b2f((ushort)(u0 >> 16));
        if (c > 1) {
            unsigned u1 = *reinterpret_cast<const unsigned*>(
                Ain + (size_t)(ss >> 16) * 128 + lo);
            ax += b2f((ushort)(u1 & 0xFFFF));
            ay += b2f((ushort)(u1 >> 16));
            for (int e = 2; e < c; ++e) {                     // rare tail (~10% of edges)
                int s = (int)bovf[(size_t)(node * RR + r) * OVF + (e - 2)];
                unsigned w = *reinterpret_cast<const unsigned*>(
                    Ain + (size_t)s * 128 + lo);
                ax += b2f((ushort)(w & 0xFFFF));
                ay += b2f((ushort)(w >> 16));
            }
        }
#pragma unroll
        for (int b = 0; b < BBASES; ++b) {
            float cf = coeff[r * BBASES + b];                 // uniform scalar
            sx[b] += cf * ax;
            sy[b] += cf * ay;
        }
    }

#pragma unroll
    for (int b = 0; b < BBASES; ++b) {
        unsigned pk = (unsigned)f2b(sx[b]) | ((unsigned)f2b(sy[b]) << 16);
        *reinterpret_cast<unsigned*>(orow + b * 128) = pk;
    }
}

// ---- dense GEMM (64 rows/block): C[64 x 128] over NS=9 K-steps.
//      K-steps 0..7 read xs (L3-resident chunk); K-step 8 (self) reads Ain directly. ----
__global__ __launch_bounds__(256, 3) void k_ggemm(
    const ushort* __restrict__ xs,    // [C][XS_S][128] chunk-local
    const ushort* __restrict__ Ain,   // [NN][128] node features (self slice)
    const ushort* __restrict__ Bt,    // [NS][128col][128k]
    const float* __restrict__ bias,
    ushort* __restrict__ hbout,
    const float* __restrict__ wagg, const float* __restrict__ bagg,
    float* __restrict__ zout, int mode, int n0)
{
    __shared__ ushort As[64 * 128];    // 16 KB
    __shared__ ushort Bs[128 * 128];   // 32 KB
    int tid = threadIdx.x;
    int wid = tid >> 6, lane = tid & 63;
    int lr = lane & 15, lk = lane >> 4;
    int loc0 = blockIdx.x * 64;        // chunk-local row base

    f32x4 acc[8];
#pragma unroll
    for (int t = 0; t < 8; ++t) acc[t] = (f32x4){0.f, 0.f, 0.f, 0.f};

    for (int kk = 0; kk < NS; ++kk) {
        __syncthreads();               // previous MFMA reads complete
        f32x4 ta[4], tb[8];
#pragma unroll
        for (int q = 0; q < 4; ++q) {
            int g = q * 256 + tid, r = g >> 4, c = g & 15;
            if (kk < XS_S) {
                ta[q] = *reinterpret_cast<const f32x4*>(
                    xs + ((size_t)(loc0 + r) * XS_S + kk) * 128 + c * 8);
            } else {
                int gr = n0 + loc0 + r;
                gr = gr < NN ? gr : NN - 1;        // clamp; tail rows discarded later
                ta[q] = *reinterpret_cast<const f32x4*>(
                    Ain + (size_t)gr * 128 + c * 8);
            }
        }
#pragma unroll
        for (int q = 0; q < 8; ++q) {
            int g = q * 256 + tid, r = g >> 4, c = g & 15;
            tb[q] = *reinterpret_cast<const f32x4*>(
                Bt + (size_t)kk * SLICE + r * 128 + c * 8);
        }
#pragma unroll
        for (int q = 0; q < 4; ++q) {
            int g = q * 256 + tid, r = g >> 4, c = g & 15;
            *(reinterpret_cast<f32x4*>(As) + (r * 16 + (c ^ (r & 7)))) = ta[q];
        }
#pragma unroll
        for (int q = 0; q < 8; ++q) {
            int g = q * 256 + tid, r = g >> 4, c = g & 15;
            *(reinterpret_cast<f32x4*>(Bs) + (r * 16 + (c ^ (r & 7)))) = tb[q];
        }
        __syncthreads();               // staging visible to all waves
#pragma unroll
        for (int j = 0; j < 4; ++j) {
            int row = wid * 16 + lr;
            short8 a = *(reinterpret_cast<const short8*>(As) +
                         (row * 16 + ((lk + 4 * j) ^ (row & 7))));
#pragma unroll
            for (int t = 0; t < 8; ++t) {
                int row2 = t * 16 + lr;
                short8 b = *(reinterpret_cast<const short8*>(Bs) +
                             (row2 * 16 + ((lk + 4 * j) ^ (row2 & 7))));
                acc[t] = __builtin_amdgcn_mfma_f32_16x16x32_bf16(a, b, acc[t], 0, 0, 0);
            }
        }
    }

    if (mode == 1) {
#pragma unroll
        for (int t = 0; t < 8; ++t) {
            int col = t * 16 + lr;
            float bc = bias[col];
#pragma unroll
            for (int j = 0; j < 4; ++j) {
                int gn = n0 + loc0 + wid * 16 + lk * 4 + j;
                if (gn < NN) {
                    float v = acc[t][j] + bc;
                    v = v >= 0.f ? v : SLOPE * v;
                    hbout[(size_t)gn * 128 + col] = f2b(v);
                }
            }
        }
    } else {
#pragma unroll
        for (int j = 0; j < 4; ++j) {
            float p = 0.f;
#pragma unroll
            for (int t = 0; t < 8; ++t) {
                int col = t * 16 + lr;
                p += (acc[t][j] + bias[col]) * wagg[col];
            }
            p += __shfl_xor(p, 1);
            p += __shfl_xor(p, 2);
            p += __shfl_xor(p, 4);
            p += __shfl_xor(p, 8);
            if (lr == 0) {
                int gn = n0 + loc0 + wid * 16 + lk * 4 + j;
                if (gn < NN) zout[gn] = p + bagg[0];
            }
        }
    }
}

// ---- dense1 stage 1: partial[bid][j] = sum over block's rows of z[n]*wd1[n,j]. ----
__global__ __launch_bounds__(256) void k_dense1(
    const float* __restrict__ z, const float* __restrict__ wd1,
    float* __restrict__ partial)
{
    __shared__ float lds[10][100];
    int tid = threadIdx.x;
    int rg = tid / 25, c = tid % 25;
    int rows_per_block = (NN + gridDim.x - 1) / gridDim.x;
    int n0 = blockIdx.x * rows_per_block;
    int n1 = min(NN, n0 + rows_per_block);
    if (rg < 10) {
        float4 acc = {0.f, 0.f, 0.f, 0.f};
        for (int n = n0 + rg; n < n1; n += 10) {
            float zv = z[n];
            float4 w = *reinterpret_cast<const float4*>(wd1 + (size_t)n * 100 + c * 4);
            acc.x += zv * w.x; acc.y += zv * w.y;
            acc.z += zv * w.z; acc.w += zv * w.w;
        }
        lds[rg][c * 4 + 0] = acc.x;
        lds[rg][c * 4 + 1] = acc.y;
        lds[rg][c * 4 + 2] = acc.z;
        lds[rg][c * 4 + 3] = acc.w;
    }
    __syncthreads();
    if (tid < 100) {
        float s = 0.f;
#pragma unroll
        for (int r = 0; r < 10; ++r) s += lds[r][tid];
        partial[blockIdx.x * 100 + tid] = s;
    }
}

// ---- final: reduce partials (8 groups x 128) + tiny MLP head ----
__global__ __launch_bounds__(1024) void k_final(
    const float* __restrict__ partial, const float* __restrict__ bd1,
    const float* __restrict__ wd2, const float* __restrict__ bd2,
    const float* __restrict__ wd3, const float* __restrict__ bd3,
    float* __restrict__ out)
{
    __shared__ float red[8][100];
    __shared__ float t1[100], t2[20];
    int t = threadIdx.x;
    int g = t >> 7, j = t & 127;
    if (j < 100) {
        float s = 0.f;
        for (int b = g; b < D1B; b += 8)
            s += partial[b * 100 + j];
        red[g][j] = s;
    }
    __syncthreads();
    if (t < 100) {
        float s = bd1[t];
#pragma unroll
        for (int r = 0; r < 8; ++r) s += red[r][t];
        t1[t] = s;
    }
    __syncthreads();
    if (t < 20) {
        float s = bd2[t];
        for (int j2 = 0; j2 < 100; ++j2) s += t1[j2] * wd2[j2 * 20 + t];
        t2[t] = s >= 0.f ? s : SLOPE * s;
    }
    __syncthreads();
    if (t < 10) {
        float s = bd3[t];
        for (int k = 0; k < 20; ++k) s += t2[k] * wd3[k * 10 + t];
        out[t] = s;
    }
}

extern "C" void kernel_launch(void* const* d_in, const int* in_sizes, int n_in,
                              void* d_out, int out_size, void* d_ws, size_t ws_size,
                              hipStream_t stream)
{
    const float* x      = (const float*)d_in[0];
    const int*   src    = (const int*)d_in[1];
    const int*   dst    = (const int*)d_in[2];
    const int*   etype  = (const int*)d_in[3];
    const float* coeff1 = (const float*)d_in[4];
    const float* basis1 = (const float*)d_in[5];
    const float* wloop1 = (const float*)d_in[6];
    const float* b1     = (const float*)d_in[7];
    const float* coeff2 = (const float*)d_in[8];
    const float* basis2 = (const float*)d_in[9];
    const float* wloop2 = (const float*)d_in[10];
    const float* b2     = (const float*)d_in[11];
    const float* wagg   = (const float*)d_in[12];
    const float* bagg   = (const float*)d_in[13];
    const float* wd1    = (const float*)d_in[14];
    const float* bd1    = (const float*)d_in[15];
    const float* wd2    = (const float*)d_in[16];
    const float* bd2    = (const float*)d_in[17];
    const float* wd3    = (const float*)d_in[18];
    const float* bd3    = (const float*)d_in[19];
    float* out = (float*)d_out;

    // ---- workspace layout: fixed buffers first, xs chunk sized from what's left ----
    char* p = (char*)d_ws;
    auto alloc = [&](size_t bytes) -> char* {
        char* q = p;
        p += (bytes + 255) & ~(size_t)255;
        return q;
    };
    ushort* Wt     = (ushort*)alloc(sizeof(ushort) * (size_t)2 * LSTRIDE);      // 0.6 MB
    ushort* xb     = (ushort*)alloc(sizeof(ushort) * (size_t)NN * 128);         // 12.8 MB
    ushort* hb     = (ushort*)alloc(sizeof(ushort) * (size_t)NN * 128);         // 12.8 MB
    int*    curNR  = (int*)alloc(sizeof(int) * (size_t)NN * RR);                // 3.2 MB
    uint*   bslot01= (uint*)alloc(sizeof(uint) * (size_t)NN * RR);              // 3.2 MB
    ushort* bovf   = (ushort*)alloc(sizeof(ushort) * (size_t)NN * RR * OVF);    // 22.4 MB
    float*  z      = (float*)alloc(sizeof(float) * NN);                         // 0.2 MB
    float*  partial= (float*)alloc(sizeof(float) * D1B * 100);                  // 0.1 MB
    size_t fixed = (size_t)(p - (char*)d_ws);
    size_t avail = ws_size > fixed ? ws_size - fixed : 0;
    // chunk size in nodes (multiple of 64), capped for L3 residency of xs
    long cmax = (long)(avail / (XS_S * 128 * sizeof(ushort)));
    int C = (int)(cmax < (long)CCAP ? cmax : (long)CCAP);
    C &= ~63;
    if (C < 64) C = 64;                 // ws smaller than anything ever tested — last resort
    ushort* xs = (ushort*)p;            // [C][XS_S][128]

    // ---- prep (Bt, x->bf16, zero curNR) + bucket ----
    k_prep<<<2048, 256, 0, stream>>>(basis1, basis2, wloop1, wloop2,
                                     x, xb, Wt, curNR);
    k_bucket<<<2048, 256, 0, stream>>>(src, dst, etype, curNR, bslot01, bovf);

    // ---- two layers, chunked over nodes ----
    for (int layer = 0; layer < 2; ++layer) {
        const ushort* Ain = layer ? hb : xb;
        const ushort* Bm  = Wt + (size_t)layer * LSTRIDE;
        const float*  cf  = layer ? coeff2 : coeff1;
        for (int n0 = 0; n0 < MROWS; n0 += C) {
            int ncnt = (MROWS - n0 < C) ? (MROWS - n0) : C;   // multiple of 64
            int gblocks = (ncnt * 64 + 255) / 256;            // one wave per node
            k_gather<<<gblocks, 256, 0, stream>>>(Ain, curNR, bslot01, bovf, cf,
                                                  xs, n0, ncnt);
            if (layer == 0)
                k_ggemm<<<ncnt / 64, 256, 0, stream>>>(
                    xs, Ain, Bm, b1, hb, nullptr, nullptr, nullptr, 1, n0);
            else
                k_ggemm<<<ncnt / 64, 256, 0, stream>>>(
                    xs, Ain, Bm, b2, nullptr, wagg, bagg, z, 2, n0);
        }
    }

    // ---- head ----
    k_dense1<<<D1B, 256, 0, stream>>>(z, wd1, partial);
    k_final<<<1, 1024, 0, stream>>>(partial, bd1, wd2, bd2, wd3, bd3, out);
}

// Round 31
// 288.406 us; speedup vs baseline: 1.0707x; 1.0707x over previous
//
#include <hip/hip_runtime.h>

#define NN 50000
#define EE 800000
#define RR 16
#define BBASES 8
#define SLOPE 0.01f
#define BCAP 16          // total per-(dst,rel) capacity (2 dense + 14 overflow)
#define OVF (BCAP - 2)
#define SLICE 16384      // 128*128 elems per W slice
#define NS 9             // slices after basis-combine: 8 basis + 1 self
#define LSTRIDE (NS * SLICE)
#define MROWS 50048      // NN padded (multiple of 64)
#define CCAP 50048       // single chunk: grid 782 blocks -> ~3 blocks/CU
#define D1B 256          // k_dense1 blocks
#define NPART 6250       // NN / 8 (dst partition width)

typedef __attribute__((ext_vector_type(8))) short short8;
typedef __attribute__((ext_vector_type(4))) float f32x4;

static __device__ __forceinline__ ushort f2b(float f) {
    unsigned u = __float_as_uint(f);
    unsigned r = (u + 0x7FFF + ((u >> 16) & 1)) >> 16;
    return (ushort)r;
}
static __device__ __forceinline__ float b2f(ushort h) {
    return __uint_as_float(((unsigned)h) << 16);
}

// ---- prep: Bt both layers (8 transposed basis slices + wloop^T) + x->bf16 + zero curNR ----
__global__ __launch_bounds__(256) void k_prep(
    const float* __restrict__ basis1, const float* __restrict__ basis2,
    const float* __restrict__ wloop1, const float* __restrict__ wloop2,
    const float* __restrict__ x, ushort* __restrict__ xb,
    ushort* __restrict__ Wt, int* __restrict__ curNR)
{
    const long WTN = 2 * BBASES * SLICE;           // 262144 (basis transpose)
    const long WLN = 2 * SLICE;                    // 32768  (wloop transpose)
    const long CVT = (long)NN * 128 / 4;           // 1.6M (4 elems each)
    const long total = WTN + WLN + CVT + (long)NN * RR;
    for (long t = (long)blockIdx.x * blockDim.x + threadIdx.x; t < total;
         t += (long)gridDim.x * blockDim.x) {
        if (t < WTN) {
            int l = (int)(t >> 17);
            int rem = (int)(t & 131071);
            int b = rem >> 14;
            int kn = rem & 16383;
            int k = kn >> 7, n = kn & 127;
            const float* bs = l ? basis2 : basis1;
            Wt[(long)l * LSTRIDE + (long)b * SLICE + n * 128 + k] =
                f2b(bs[(long)b * SLICE + kn]);
        } else if (t < WTN + WLN) {
            int j = (int)(t - WTN);
            int l = j >> 14;
            int kn = j & 16383;
            int k = kn >> 7, n = kn & 127;
            const float* wl = l ? wloop2 : wloop1;
            Wt[(long)l * LSTRIDE + (NS - 1) * SLICE + n * 128 + k] = f2b(wl[kn]);
        } else if (t < WTN + WLN + CVT) {
            long i = t - WTN - WLN;
            float4 v = reinterpret_cast<const float4*>(x)[i];
            ushort4 o;
            o.x = f2b(v.x); o.y = f2b(v.y); o.z = f2b(v.z); o.w = f2b(v.w);
            reinterpret_cast<ushort4*>(xb)[i] = o;
        } else {
            curNR[(long)(t - WTN - WLN - CVT)] = 0;
        }
    }
}

// ---- bucket edges by (dst, rel), dst-partitioned by blockIdx&7 (XCD heuristic) ----
__global__ __launch_bounds__(256) void k_bucket(
    const int* __restrict__ src, const int* __restrict__ dst,
    const int* __restrict__ etype, int* __restrict__ curNR,
    uint* __restrict__ bslot01, ushort* __restrict__ bovf)
{
    int part = blockIdx.x & 7;
    int bg = blockIdx.x >> 3;               // 0..255 block-groups per partition
    int dlo = part * NPART, dhi = dlo + NPART;
    for (long t = (long)bg * blockDim.x + threadIdx.x; t < EE;
         t += 256L * blockDim.x) {
        int d = __builtin_nontemporal_load(dst + t);
        if (d < dlo || d >= dhi) continue;
        int e = __builtin_nontemporal_load(etype + t);
        int s = __builtin_nontemporal_load(src + t);
        int idx = d * RR + e;
        int pos = atomicAdd(curNR + idx, 1);
        if (pos < 2)
            reinterpret_cast<ushort*>(bslot01)[idx * 2 + pos] = (ushort)s;
        else if (pos < BCAP)
            bovf[(size_t)idx * OVF + (pos - 2)] = (ushort)s;
    }
}

// ---- gather+combine: one wave per node. Per relation r compute edge-sum (f32),
//      accumulate into 8 basis-combo accumulators via coeff[r][b] (uniform scalars).
//      xs[i][b][:] = bf16(sum_r coeff[r,b]*relsum_r), xs[i][8][:] = Ain[node]. ----
__global__ __launch_bounds__(256) void k_gather(
    const ushort* __restrict__ Ain,    // [NN][128] bf16
    const int* __restrict__ cnt,       // [NN*16]
    const uint* __restrict__ bslot01,  // [NN*16] slot0|slot1 packed
    const ushort* __restrict__ bovf,   // [NN*16][OVF]
    const float* __restrict__ coeff,   // [RR][BBASES] (layer-specific)
    ushort* __restrict__ xs,           // [C][NS][128] bf16 (chunk-local)
    int n0, int ncnt)
{
    int idx = (int)(((long)blockIdx.x * blockDim.x + threadIdx.x) >> 6);
    int lane = threadIdx.x & 63;
    if (idx >= ncnt) return;
    int node = __builtin_amdgcn_readfirstlane(n0 + idx);
    if (node >= NN) return;
    int lo = lane * 2;

    ushort* orow = xs + (size_t)idx * (NS * 128) + lo;

    // self row: verbatim copy
    {
        unsigned self = *reinterpret_cast<const unsigned*>(Ain + (size_t)node * 128 + lo);
        *reinterpret_cast<unsigned*>(orow + (NS - 1) * 128) = self;
    }

    float sx[BBASES], sy[BBASES];
#pragma unroll
    for (int b = 0; b < BBASES; ++b) { sx[b] = 0.f; sy[b] = 0.f; }

#pragma unroll 4
    for (int r = 0; r < RR; ++r) {
        int c = cnt[node * RR + r];                          // wave-uniform -> scalar load
        c = min(c, BCAP);
        if (c == 0) continue;
        unsigned ss = bslot01[node * RR + r];                 // slot0|slot1, scalar load
        unsigned u0 = *reinterpret_cast<const unsigned*>(
            Ain + (size_t)(ss & 0xFFFFu) * 128 + lo);
        float ax = b2f((ushort)(u0 & 0xFFFF));
        float ay = b2f((ushort)(u0 >> 16));
        if (c > 1) {
            unsigned u1 = *reinterpret_cast<const unsigned*>(
                Ain + (size_t)(ss >> 16) * 128 + lo);
            ax += b2f((ushort)(u1 & 0xFFFF));
            ay += b2f((ushort)(u1 >> 16));
            for (int e = 2; e < c; ++e) {                     // rare tail (~10% of edges)
                int s = (int)bovf[(size_t)(node * RR + r) * OVF + (e - 2)];
                unsigned w = *reinterpret_cast<const unsigned*>(
                    Ain + (size_t)s * 128 + lo);
                ax += b2f((ushort)(w & 0xFFFF));
                ay += b2f((ushort)(w >> 16));
            }
        }
#pragma unroll
        for (int b = 0; b < BBASES; ++b) {
            float cf = coeff[r * BBASES + b];                 // uniform scalar
            sx[b] += cf * ax;
            sy[b] += cf * ay;
        }
    }

#pragma unroll
    for (int b = 0; b < BBASES; ++b) {
        unsigned pk = (unsigned)f2b(sx[b]) | ((unsigned)f2b(sy[b]) << 16);
        *reinterpret_cast<unsigned*>(orow + b * 128) = pk;
    }
}

// ---- dense GEMM (64 rows/block): C[64 x 128] = xs_local @ Bt^T (NS=9 K-steps).
//      Within-iteration staging only (cross-barrier reg prefetch spills — measured 2x). ----
__global__ __launch_bounds__(256, 3) void k_ggemm(
    const ushort* __restrict__ xs,    // [C][NS][128] chunk-local
    const ushort* __restrict__ Bt,    // [NS][128col][128k]
    const float* __restrict__ bias,
    ushort* __restrict__ hbout,
    const float* __restrict__ wagg, const float* __restrict__ bagg,
    float* __restrict__ zout, int mode, int n0)
{
    __shared__ ushort As[64 * 128];    // 16 KB
    __shared__ ushort Bs[128 * 128];   // 32 KB
    int tid = threadIdx.x;
    int wid = tid >> 6, lane = tid & 63;
    int lr = lane & 15, lk = lane >> 4;
    int loc0 = blockIdx.x * 64;        // chunk-local row base

    f32x4 acc[8];
#pragma unroll
    for (int t = 0; t < 8; ++t) acc[t] = (f32x4){0.f, 0.f, 0.f, 0.f};

    for (int kk = 0; kk < NS; ++kk) {
        __syncthreads();               // previous MFMA reads complete
        float4 ta[4], tb[8];
#pragma unroll
        for (int q = 0; q < 4; ++q) {
            int g = q * 256 + tid, r = g >> 4, c = g & 15;
            ta[q] = *reinterpret_cast<const float4*>(
                xs + ((size_t)(loc0 + r) * NS + kk) * 128 + c * 8);
        }
#pragma unroll
        for (int q = 0; q < 8; ++q) {
            int g = q * 256 + tid, r = g >> 4, c = g & 15;
            tb[q] = *reinterpret_cast<const float4*>(
                Bt + (size_t)kk * SLICE + r * 128 + c * 8);
        }
#pragma unroll
        for (int q = 0; q < 4; ++q) {
            int g = q * 256 + tid, r = g >> 4, c = g & 15;
            *(reinterpret_cast<float4*>(As) + (r * 16 + (c ^ (r & 7)))) = ta[q];
        }
#pragma unroll
        for (int q = 0; q < 8; ++q) {
            int g = q * 256 + tid, r = g >> 4, c = g & 15;
            *(reinterpret_cast<float4*>(Bs) + (r * 16 + (c ^ (r & 7)))) = tb[q];
        }
        __syncthreads();               // staging visible to all waves
#pragma unroll
        for (int j = 0; j < 4; ++j) {
            int row = wid * 16 + lr;
            short8 a = *(reinterpret_cast<const short8*>(As) +
                         (row * 16 + ((lk + 4 * j) ^ (row & 7))));
#pragma unroll
            for (int t = 0; t < 8; ++t) {
                int row2 = t * 16 + lr;
                short8 b = *(reinterpret_cast<const short8*>(Bs) +
                             (row2 * 16 + ((lk + 4 * j) ^ (row2 & 7))));
                acc[t] = __builtin_amdgcn_mfma_f32_16x16x32_bf16(a, b, acc[t], 0, 0, 0);
            }
        }
    }

    if (mode == 1) {
#pragma unroll
        for (int t = 0; t < 8; ++t) {
            int col = t * 16 + lr;
            float bc = bias[col];
#pragma unroll
            for (int j = 0; j < 4; ++j) {
                int gn = n0 + loc0 + wid * 16 + lk * 4 + j;
                if (gn < NN) {
                    float v = acc[t][j] + bc;
                    v = v >= 0.f ? v : SLOPE * v;
                    hbout[(size_t)gn * 128 + col] = f2b(v);
                }
            }
        }
    } else {
#pragma unroll
        for (int j = 0; j < 4; ++j) {
            float p = 0.f;
#pragma unroll
            for (int t = 0; t < 8; ++t) {
                int col = t * 16 + lr;
                p += (acc[t][j] + bias[col]) * wagg[col];
            }
            p += __shfl_xor(p, 1);
            p += __shfl_xor(p, 2);
            p += __shfl_xor(p, 4);
            p += __shfl_xor(p, 8);
            if (lr == 0) {
                int gn = n0 + loc0 + wid * 16 + lk * 4 + j;
                if (gn < NN) zout[gn] = p + bagg[0];
            }
        }
    }
}

// ---- dense1 stage 1: partial[bid][j] = sum over block's rows of z[n]*wd1[n,j]. ----
__global__ __launch_bounds__(256) void k_dense1(
    const float* __restrict__ z, const float* __restrict__ wd1,
    float* __restrict__ partial)
{
    __shared__ float lds[10][100];
    int tid = threadIdx.x;
    int rg = tid / 25, c = tid % 25;
    int rows_per_block = (NN + gridDim.x - 1) / gridDim.x;
    int n0 = blockIdx.x * rows_per_block;
    int n1 = min(NN, n0 + rows_per_block);
    if (rg < 10) {
        float4 acc = {0.f, 0.f, 0.f, 0.f};
        for (int n = n0 + rg; n < n1; n += 10) {
            float zv = z[n];
            float4 w = *reinterpret_cast<const float4*>(wd1 + (size_t)n * 100 + c * 4);
            acc.x += zv * w.x; acc.y += zv * w.y;
            acc.z += zv * w.z; acc.w += zv * w.w;
        }
        lds[rg][c * 4 + 0] = acc.x;
        lds[rg][c * 4 + 1] = acc.y;
        lds[rg][c * 4 + 2] = acc.z;
        lds[rg][c * 4 + 3] = acc.w;
    }
    __syncthreads();
    if (tid < 100) {
        float s = 0.f;
#pragma unroll
        for (int r = 0; r < 10; ++r) s += lds[r][tid];
        partial[blockIdx.x * 100 + tid] = s;
    }
}

// ---- final: reduce partials (8 groups x 128) + tiny MLP head ----
__global__ __launch_bounds__(1024) void k_final(
    const float* __restrict__ partial, const float* __restrict__ bd1,
    const float* __restrict__ wd2, const float* __restrict__ bd2,
    const float* __restrict__ wd3, const float* __restrict__ bd3,
    float* __restrict__ out)
{
    __shared__ float red[8][100];
    __shared__ float t1[100], t2[20];
    int t = threadIdx.x;
    int g = t >> 7, j = t & 127;
    if (j < 100) {
        float s = 0.f;
        for (int b = g; b < D1B; b += 8)
            s += partial[b * 100 + j];
        red[g][j] = s;
    }
    __syncthreads();
    if (t < 100) {
        float s = bd1[t];
#pragma unroll
        for (int r = 0; r < 8; ++r) s += red[r][t];
        t1[t] = s;
    }
    __syncthreads();
    if (t < 20) {
        float s = bd2[t];
        for (int j2 = 0; j2 < 100; ++j2) s += t1[j2] * wd2[j2 * 20 + t];
        t2[t] = s >= 0.f ? s : SLOPE * s;
    }
    __syncthreads();
    if (t < 10) {
        float s = bd3[t];
        for (int k = 0; k < 20; ++k) s += t2[k] * wd3[k * 10 + t];
        out[t] = s;
    }
}

extern "C" void kernel_launch(void* const* d_in, const int* in_sizes, int n_in,
                              void* d_out, int out_size, void* d_ws, size_t ws_size,
                              hipStream_t stream)
{
    const float* x      = (const float*)d_in[0];
    const int*   src    = (const int*)d_in[1];
    const int*   dst    = (const int*)d_in[2];
    const int*   etype  = (const int*)d_in[3];
    const float* coeff1 = (const float*)d_in[4];
    const float* basis1 = (const float*)d_in[5];
    const float* wloop1 = (const float*)d_in[6];
    const float* b1     = (const float*)d_in[7];
    const float* coeff2 = (const float*)d_in[8];
    const float* basis2 = (const float*)d_in[9];
    const float* wloop2 = (const float*)d_in[10];
    const float* b2     = (const float*)d_in[11];
    const float* wagg   = (const float*)d_in[12];
    const float* bagg   = (const float*)d_in[13];
    const float* wd1    = (const float*)d_in[14];
    const float* bd1    = (const float*)d_in[15];
    const float* wd2    = (const float*)d_in[16];
    const float* bd2    = (const float*)d_in[17];
    const float* wd3    = (const float*)d_in[18];
    const float* bd3    = (const float*)d_in[19];
    float* out = (float*)d_out;

    // ---- workspace layout: fixed buffers first, xs chunk sized from what's left ----
    char* p = (char*)d_ws;
    auto alloc = [&](size_t bytes) -> char* {
        char* q = p;
        p += (bytes + 255) & ~(size_t)255;
        return q;
    };
    ushort* Wt     = (ushort*)alloc(sizeof(ushort) * (size_t)2 * LSTRIDE);      // 0.6 MB
    ushort* xb     = (ushort*)alloc(sizeof(ushort) * (size_t)NN * 128);         // 12.8 MB
    ushort* hb     = (ushort*)alloc(sizeof(ushort) * (size_t)NN * 128);         // 12.8 MB
    int*    curNR  = (int*)alloc(sizeof(int) * (size_t)NN * RR);                // 3.2 MB
    uint*   bslot01= (uint*)alloc(sizeof(uint) * (size_t)NN * RR);              // 3.2 MB
    ushort* bovf   = (ushort*)alloc(sizeof(ushort) * (size_t)NN * RR * OVF);    // 22.4 MB
    float*  z      = (float*)alloc(sizeof(float) * NN);                         // 0.2 MB
    float*  partial= (float*)alloc(sizeof(float) * D1B * 100);                  // 0.1 MB
    size_t fixed = (size_t)(p - (char*)d_ws);
    size_t avail = ws_size > fixed ? ws_size - fixed : 0;
    // chunk size in nodes (multiple of 64); full problem if ws allows
    long cmax = (long)(avail / (NS * 128 * sizeof(ushort)));
    int C = (int)(cmax < (long)CCAP ? cmax : (long)CCAP);
    C &= ~63;
    if (C < 64) C = 64;                 // ws smaller than anything ever tested — last resort
    ushort* xs = (ushort*)p;            // [C][NS][128]

    // ---- prep (Bt, x->bf16, zero curNR) + bucket ----
    k_prep<<<2048, 256, 0, stream>>>(basis1, basis2, wloop1, wloop2,
                                     x, xb, Wt, curNR);
    k_bucket<<<2048, 256, 0, stream>>>(src, dst, etype, curNR, bslot01, bovf);

    // ---- two layers, chunked over nodes (single chunk when ws allows) ----
    for (int layer = 0; layer < 2; ++layer) {
        const ushort* Ain = layer ? hb : xb;
        const ushort* Bm  = Wt + (size_t)layer * LSTRIDE;
        const float*  cf  = layer ? coeff2 : coeff1;
        for (int n0 = 0; n0 < MROWS; n0 += C) {
            int ncnt = (MROWS - n0 < C) ? (MROWS - n0) : C;   // multiple of 64
            int gblocks = (ncnt * 64 + 255) / 256;            // one wave per node
            k_gather<<<gblocks, 256, 0, stream>>>(Ain, curNR, bslot01, bovf, cf,
                                                  xs, n0, ncnt);
            if (layer == 0)
                k_ggemm<<<ncnt / 64, 256, 0, stream>>>(
                    xs, Bm, b1, hb, nullptr, nullptr, nullptr, 1, n0);
            else
                k_ggemm<<<ncnt / 64, 256, 0, stream>>>(
                    xs, Bm, b2, nullptr, wagg, bagg, z, 2, n0);
        }
    }

    // ---- head ----
    k_dense1<<<D1B, 256, 0, stream>>>(z, wd1, partial);
    k_final<<<1, 1024, 0, stream>>>(partial, bd1, wd2, bd2, wd3, bd3, out);
}